// Round 1
// baseline (282.360 us; speedup 1.0000x reference)
//
#include <hip/hip_runtime.h>

// Focal loss (gamma=2, w0=w1=1) mean-reduction over N=2^25 elements.
// per_el = t==1 ? log(p)*(1-p)^2 : log(1-p)*p^2
//        = log(s)*(1-s)^2  with  s = (t==1 ? p : 1-p)   <-- single log per element
// Output: -mean(per_el), one fp32 scalar.
// Memory-bound: 256 MiB read once -> ~43 us floor at 6.3 TB/s.

constexpr int   N_TOTAL = 33554432;
constexpr float NEG_INV_N = -1.0f / 33554432.0f;

__global__ __launch_bounds__(256) void focal_loss_kernel(
    const float4* __restrict__ inp,
    const int4*  __restrict__ tgt,
    float* __restrict__ out,
    int n_vec)
{
    int tid    = blockIdx.x * blockDim.x + threadIdx.x;
    int stride = gridDim.x * blockDim.x;

    float acc = 0.0f;
    for (int i = tid; i < n_vec; i += stride) {
        float4 p4 = inp[i];
        int4   t4 = tgt[i];
        float p[4] = {p4.x, p4.y, p4.z, p4.w};
        int   t[4] = {t4.x, t4.y, t4.z, t4.w};
#pragma unroll
        for (int j = 0; j < 4; ++j) {
            float s = (t[j] == 1) ? p[j] : (1.0f - p[j]);
            float q = 1.0f - s;
            acc += __logf(s) * q * q;
        }
    }

    // wave-64 shuffle reduction
#pragma unroll
    for (int off = 32; off > 0; off >>= 1)
        acc += __shfl_down(acc, off, 64);

    __shared__ float ws[4];  // 256 threads = 4 waves
    int lane = threadIdx.x & 63;
    int wave = threadIdx.x >> 6;
    if (lane == 0) ws[wave] = acc;
    __syncthreads();

    if (threadIdx.x == 0) {
        float b = ws[0] + ws[1] + ws[2] + ws[3];
        atomicAdd(out, b * NEG_INV_N);  // one device-scope atomic per block
    }
}

extern "C" void kernel_launch(void* const* d_in, const int* in_sizes, int n_in,
                              void* d_out, int out_size, void* d_ws, size_t ws_size,
                              hipStream_t stream) {
    const float4* inp = (const float4*)d_in[0];
    const int4*   tgt = (const int4*)d_in[1];
    float*        out = (float*)d_out;

    int n_vec = N_TOTAL / 4;  // 8388608 float4/int4 elements

    // d_out is re-poisoned to 0xAA before every timed launch; zero it
    // (async memset is graph-capture-safe).
    hipMemsetAsync(d_out, 0, sizeof(float), stream);

    // 2048 blocks x 256 threads: 8 blocks/CU across 256 CUs; each thread
    // does 16 float4 iterations.
    focal_loss_kernel<<<2048, 256, 0, stream>>>(inp, tgt, out, n_vec);
}

// Round 2
// 277.248 us; speedup vs baseline: 1.0184x; 1.0184x over previous
//
#include <hip/hip_runtime.h>

// Focal loss (gamma=2, w0=w1=1) mean-reduction over N=2^25 elements.
// per_el = t==1 ? log(p)*(1-p)^2 : log(1-p)*p^2
//        = log(s)*(1-s)^2  with  s = (t==1 ? p : 1-p)   <-- single log per element
// Output: -mean(per_el), one fp32 scalar.
//
// R1 post-mortem: atomicAdd from 2048 blocks to ONE address serialized the
// tail (~60 us), and the rolled grid-stride loop kept only 1 load-pair in
// flight. R2: two-stage reduction (block partials -> d_ws -> tiny reduce
// kernel, zero atomics) + static partition with x4 unrolled loads (8
// independent global_load_dwordx4 in flight per iteration).

constexpr int   N_TOTAL   = 33554432;
constexpr int   N_VEC     = N_TOTAL / 4;        // 8388608 float4 elements
constexpr int   BLOCKS    = 2048;
constexpr int   THREADS   = 256;
constexpr int   VEC_PER_BLOCK = N_VEC / BLOCKS; // 4096
constexpr int   ITERS     = VEC_PER_BLOCK / THREADS; // 16
constexpr float NEG_INV_N = -1.0f / 33554432.0f;

__device__ __forceinline__ float focal_term(float p, int t) {
    float s = (t == 1) ? p : (1.0f - p);
    float q = 1.0f - s;
    return __logf(s) * q * q;
}

__global__ __launch_bounds__(THREADS) void focal_partial_kernel(
    const float4* __restrict__ inp,
    const int4*  __restrict__ tgt,
    float* __restrict__ partials)
{
    const int base = blockIdx.x * VEC_PER_BLOCK + threadIdx.x;

    float acc = 0.0f;
#pragma unroll
    for (int it = 0; it < ITERS; it += 4) {
        // 8 independent 16B loads issued back-to-back before any consume.
        float4 p0 = inp[base + (it + 0) * THREADS];
        float4 p1 = inp[base + (it + 1) * THREADS];
        float4 p2 = inp[base + (it + 2) * THREADS];
        float4 p3 = inp[base + (it + 3) * THREADS];
        int4   t0 = tgt[base + (it + 0) * THREADS];
        int4   t1 = tgt[base + (it + 1) * THREADS];
        int4   t2 = tgt[base + (it + 2) * THREADS];
        int4   t3 = tgt[base + (it + 3) * THREADS];

        acc += focal_term(p0.x, t0.x) + focal_term(p0.y, t0.y)
             + focal_term(p0.z, t0.z) + focal_term(p0.w, t0.w);
        acc += focal_term(p1.x, t1.x) + focal_term(p1.y, t1.y)
             + focal_term(p1.z, t1.z) + focal_term(p1.w, t1.w);
        acc += focal_term(p2.x, t2.x) + focal_term(p2.y, t2.y)
             + focal_term(p2.z, t2.z) + focal_term(p2.w, t2.w);
        acc += focal_term(p3.x, t3.x) + focal_term(p3.y, t3.y)
             + focal_term(p3.z, t3.z) + focal_term(p3.w, t3.w);
    }

    // wave-64 shuffle reduction
#pragma unroll
    for (int off = 32; off > 0; off >>= 1)
        acc += __shfl_down(acc, off, 64);

    __shared__ float ws[THREADS / 64];
    int lane = threadIdx.x & 63;
    int wave = threadIdx.x >> 6;
    if (lane == 0) ws[wave] = acc;
    __syncthreads();

    if (threadIdx.x == 0)
        partials[blockIdx.x] = ws[0] + ws[1] + ws[2] + ws[3];  // plain store, no atomic
}

__global__ __launch_bounds__(THREADS) void focal_final_kernel(
    const float* __restrict__ partials,
    float* __restrict__ out)
{
    // 2048 partials / 256 threads = 8 each
    float acc = 0.0f;
#pragma unroll
    for (int k = 0; k < BLOCKS / THREADS; ++k)
        acc += partials[k * THREADS + threadIdx.x];

#pragma unroll
    for (int off = 32; off > 0; off >>= 1)
        acc += __shfl_down(acc, off, 64);

    __shared__ float ws[THREADS / 64];
    int lane = threadIdx.x & 63;
    int wave = threadIdx.x >> 6;
    if (lane == 0) ws[wave] = acc;
    __syncthreads();

    if (threadIdx.x == 0)
        out[0] = (ws[0] + ws[1] + ws[2] + ws[3]) * NEG_INV_N;  // overwrites poison
}

extern "C" void kernel_launch(void* const* d_in, const int* in_sizes, int n_in,
                              void* d_out, int out_size, void* d_ws, size_t ws_size,
                              hipStream_t stream) {
    const float4* inp = (const float4*)d_in[0];
    const int4*   tgt = (const int4*)d_in[1];
    float*        out = (float*)d_out;
    float*        partials = (float*)d_ws;  // 2048 floats = 8 KB scratch

    focal_partial_kernel<<<BLOCKS, THREADS, 0, stream>>>(inp, tgt, partials);
    focal_final_kernel<<<1, THREADS, 0, stream>>>(partials, out);
}

// Round 3
// 247.102 us; speedup vs baseline: 1.1427x; 1.1220x over previous
//
#include <hip/hip_runtime.h>

// Focal loss (gamma=2, w0=w1=1) mean over N=2^25: -mean(log(s)*(1-s)^2),
// s = t ? p : 1-p. Two-stage reduction (no atomics).
//
// R2 post-mortem: static x4 unroll changed NOTHING (104 us, 2.58 TB/s
// delivered, VALUBusy 16%) -> convoy/latency-bound, not BW- or VALU-bound.
// VGPR=24 proves the compiler did no cross-iteration pipelining.
// R3: (a) explicit register double-buffer (prefetch next 8 vectors while
// computing current 8), (b) nontemporal loads (nt) for read-once streams.
// FETCH_SIZE disambiguates: nt-bypass -> FETCH ~doubles; pipelining -> same.

typedef float v4f __attribute__((ext_vector_type(4)));
typedef int   v4i __attribute__((ext_vector_type(4)));

constexpr int   N_TOTAL = 33554432;
constexpr int   N_VEC   = N_TOTAL / 4;        // 8388608 float4
constexpr int   THREADS = 256;
constexpr int   BLOCKS  = 2048;
constexpr int   VPB     = N_VEC / BLOCKS;     // 4096 vec4 per block
constexpr int   PAIRS   = VPB / THREADS;      // 16 vec4-pairs per thread
constexpr int   GSIZE   = 4;                  // pairs per pipeline group
constexpr int   GROUPS  = PAIRS / GSIZE;      // 4 groups
constexpr float NEG_INV_N = -1.0f / 33554432.0f;

__device__ __forceinline__ float term4(v4f p, v4i t) {
    float r = 0.0f;
#pragma unroll
    for (int j = 0; j < 4; ++j) {
        float s = (t[j] == 1) ? p[j] : (1.0f - p[j]);
        float q = 1.0f - s;
        r += __logf(s) * q * q;
    }
    return r;
}

__global__ __launch_bounds__(THREADS) void focal_partial_kernel(
    const v4f* __restrict__ inp,
    const v4i* __restrict__ tgt,
    float* __restrict__ partials)
{
    const int base = blockIdx.x * VPB + threadIdx.x;

    v4f pbuf[2][GSIZE];
    v4i tbuf[2][GSIZE];

    // prologue: issue group 0's 8 loads (nontemporal: read-once stream)
#pragma unroll
    for (int k = 0; k < GSIZE; ++k) {
        int idx = base + k * THREADS;
        pbuf[0][k] = __builtin_nontemporal_load(&inp[idx]);
        tbuf[0][k] = __builtin_nontemporal_load(&tgt[idx]);
    }

    float acc = 0.0f;
#pragma unroll
    for (int g = 0; g < GROUPS; ++g) {
        const int cur = g & 1, nxt = cur ^ 1;
        // prefetch group g+1 BEFORE consuming group g: its 8 loads are in
        // flight during the compute below (breaks the convoy stall).
        if (g + 1 < GROUPS) {
#pragma unroll
            for (int k = 0; k < GSIZE; ++k) {
                int idx = base + ((g + 1) * GSIZE + k) * THREADS;
                pbuf[nxt][k] = __builtin_nontemporal_load(&inp[idx]);
                tbuf[nxt][k] = __builtin_nontemporal_load(&tgt[idx]);
            }
        }
#pragma unroll
        for (int k = 0; k < GSIZE; ++k)
            acc += term4(pbuf[cur][k], tbuf[cur][k]);
    }

    // wave-64 shuffle reduction
#pragma unroll
    for (int off = 32; off > 0; off >>= 1)
        acc += __shfl_down(acc, off, 64);

    __shared__ float ws[THREADS / 64];
    int lane = threadIdx.x & 63;
    int wave = threadIdx.x >> 6;
    if (lane == 0) ws[wave] = acc;
    __syncthreads();

    if (threadIdx.x == 0)
        partials[blockIdx.x] = ws[0] + ws[1] + ws[2] + ws[3];
}

__global__ __launch_bounds__(THREADS) void focal_final_kernel(
    const float* __restrict__ partials,
    float* __restrict__ out)
{
    float acc = 0.0f;
#pragma unroll
    for (int k = 0; k < BLOCKS / THREADS; ++k)
        acc += partials[k * THREADS + threadIdx.x];

#pragma unroll
    for (int off = 32; off > 0; off >>= 1)
        acc += __shfl_down(acc, off, 64);

    __shared__ float ws[THREADS / 64];
    int lane = threadIdx.x & 63;
    int wave = threadIdx.x >> 6;
    if (lane == 0) ws[wave] = acc;
    __syncthreads();

    if (threadIdx.x == 0)
        out[0] = (ws[0] + ws[1] + ws[2] + ws[3]) * NEG_INV_N;
}

extern "C" void kernel_launch(void* const* d_in, const int* in_sizes, int n_in,
                              void* d_out, int out_size, void* d_ws, size_t ws_size,
                              hipStream_t stream) {
    const v4f* inp = (const v4f*)d_in[0];
    const v4i* tgt = (const v4i*)d_in[1];
    float*     out = (float*)d_out;
    float*     partials = (float*)d_ws;   // 8 KB scratch

    focal_partial_kernel<<<BLOCKS, THREADS, 0, stream>>>(inp, tgt, partials);
    focal_final_kernel<<<1, THREADS, 0, stream>>>(partials, out);
}